// Round 7
// baseline (28.711 us; speedup 1.0000x reference)
//
#include <hip/hip_runtime.h>
#include <hip/hip_bf16.h>

#define INF_SENT 1.0e6f
#define ALPHA 1.0f
#define INV_BETA 0.5f

#define B_ 16
#define H_ 256
#define W_ 256
#define SEG 8
#define NSEG 32           // H_/SEG
#define NBLK (B_ * NSEG)  // 512 blocks

// ---------------------------------------------------------------------------
// K1: per-segment summaries for the vertical prefix/suffix min; also zeroes
// the fixed-point accumulator + completion counter used by K2's finalize.
//   sumA[b,s,j] = min_{i in seg} (init[i] - i)   (init = mask?0:1e6)
//   sumB[b,s,j] = min_{i in seg} (init[i] + i)
// ---------------------------------------------------------------------------
__global__ void edt_seg_summary(const int* __restrict__ mask,
                                float* __restrict__ sumA,
                                float* __restrict__ sumB,
                                unsigned long long* __restrict__ acc,
                                unsigned int* __restrict__ cnt) {
    const int bs = blockIdx.x;
    if (bs == 0 && threadIdx.x == 0) { acc[0] = 0ull; cnt[0] = 0u; }
    const int b  = bs >> 5;
    const int s  = bs & (NSEG - 1);
    const int j  = threadIdx.x;
    const int i0 = s * SEG;
    const long base = ((long)b * H_ + i0) * W_ + j;

    float mA = 1e30f, mB = 1e30f;
    #pragma unroll
    for (int r = 0; r < SEG; ++r) {
        float init = mask[base + (long)r * W_] ? 0.0f : INF_SENT;
        float fi = (float)(i0 + r);
        mA = fminf(mA, init - fi);
        mB = fminf(mB, init + fi);
    }
    sumA[(long)bs * W_ + j] = mA;
    sumB[(long)bs * W_ + j] = mB;
}

// ---------------------------------------------------------------------------
// K2: fused per-segment loss (identical compute core to R5) + deterministic
// last-block finalize (fixed-point u64 atomic, one vmcnt wait per block —
// NO threadfence).
//
// Early-exit exactness: every skipped term fl(g2[k]+d2) >= d2 >= best
// (round-to-nearest monotone, operands non-negative, d2 representable).
// ---------------------------------------------------------------------------
__global__ void fused_loss_kernel(const float* __restrict__ pred,
                                  const int* __restrict__ mask,
                                  const float* __restrict__ sumA,
                                  const float* __restrict__ sumB,
                                  unsigned long long* __restrict__ acc,
                                  unsigned int* __restrict__ cnt,
                                  float* __restrict__ out) {
    const int bs = blockIdx.x;
    const int b  = bs >> 5;
    const int s  = bs & (NSEG - 1);
    const int j  = threadIdx.x;
    const int i0 = s * SEG;
    const long base = ((long)b * H_ + i0) * W_ + j;

    __shared__ float s_g2[SEG][W_];
    __shared__ float s_part[4];

    // carries from the other segments of this (b, j) column
    const float* sA = sumA + (long)b * NSEG * W_ + j;
    const float* sB = sumB + (long)b * NSEG * W_ + j;
    float carryP = 1e30f, carryS = 1e30f;
    #pragma unroll
    for (int sp = 0; sp < NSEG; ++sp) {
        float a  = sA[(long)sp * W_];
        float bb = sB[(long)sp * W_];
        carryP = fminf(carryP, (sp < s) ? a  : 1e30f);
        carryS = fminf(carryS, (sp > s) ? bb : 1e30f);
    }

    float init[SEG];
    #pragma unroll
    for (int r = 0; r < SEG; ++r)
        init[r] = mask[base + (long)r * W_] ? 0.0f : INF_SENT;

    // exact vertical distances
    float F[SEG];
    float P = carryP;
    #pragma unroll
    for (int r = 0; r < SEG; ++r) {
        float fi = (float)(i0 + r);
        P = fminf(P, init[r] - fi);
        F[r] = fi + P;
    }
    float S = carryS;
    #pragma unroll
    for (int r = SEG - 1; r >= 0; --r) {
        float fi = (float)(i0 + r);
        S = fminf(S, init[r] + fi);
        float g = fminf(F[r], S - fi);
        s_g2[r][j] = g * g;
    }
    __syncthreads();

    // per-row adaptive exact horizontal min + CE + weight
    float vsum = 0.0f;
    #pragma unroll
    for (int r = 0; r < SEG; ++r) {
        float best = s_g2[r][j];
        for (int d = 1; d < W_; ++d) {
            float d2 = (float)(d * d);
            if (d2 >= best) break;
            int kl = j - d, kr = j + d;
            if (kl >= 0)  best = fminf(best, s_g2[r][kl] + d2);
            if (kr < W_)  best = fminf(best, s_g2[r][kr] + d2);
        }
        float w = __expf(-sqrtf(best) * INV_BETA);   // 0 when no bright points

        const long pbase = (((long)b * 2) * H_ + (i0 + r)) * W_ + j;
        float p0 = pred[pbase];
        float p1 = pred[pbase + (long)H_ * W_];
        // 2-class CE = softplus(-(p_t - p_other))
        float z  = (init[r] == 0.0f) ? (p1 - p0) : (p0 - p1);
        float ce = __logf(1.0f + __expf(-z));

        vsum += ce * (1.0f + ALPHA * w);
    }

    // block reduction -> one partial
    for (int off = 32; off > 0; off >>= 1)
        vsum += __shfl_down(vsum, off, 64);
    const int lane = j & 63;
    const int wid  = j >> 6;
    if (lane == 0) s_part[wid] = vsum;
    __syncthreads();

    if (j == 0) {
        float bsum = s_part[0] + s_part[1] + s_part[2] + s_part[3];  // >= 0
        // fixed-point (x 2^20) via double: deterministic, assoc. int adds
        unsigned long long fx =
            (unsigned long long)(long long)((double)bsum * 1048576.0);
        unsigned long long old = atomicAdd(acc, fx);
        asm volatile("" : "+v"(old));                 // materialize result
        asm volatile("s_waitcnt vmcnt(0)" ::: "memory"); // acc-add complete
        unsigned int oldc = atomicAdd(cnt, 1u);
        if (oldc == NBLK - 1) {
            unsigned long long total = atomicAdd(acc, 0ull); // coherent read
            out[0] = (float)((double)total *
                             (1.0 / (1048576.0 * 1048576.0))); // /2^20 /(B*H*W)
        }
    }
}

extern "C" void kernel_launch(void* const* d_in, const int* in_sizes, int n_in,
                              void* d_out, int out_size, void* d_ws, size_t ws_size,
                              hipStream_t stream) {
    const float* pred = (const float*)d_in[0];          // [B,2,H,W] f32
    const int*   mask = (const int*)d_in[1];            // [B,H,W] i32
    float* out = (float*)d_out;

    const size_t n_sum = (size_t)B_ * NSEG * W_;        // 128K floats each

    float* sumA = (float*)d_ws;
    float* sumB = sumA + n_sum;
    unsigned long long* acc = (unsigned long long*)(sumB + n_sum);
    unsigned int*       cnt = (unsigned int*)(acc + 1);

    edt_seg_summary<<<NBLK, W_, 0, stream>>>(mask, sumA, sumB, acc, cnt);
    fused_loss_kernel<<<NBLK, W_, 0, stream>>>(pred, mask, sumA, sumB,
                                               acc, cnt, out);
}

// Round 8
// 16.148 us; speedup vs baseline: 1.7780x; 1.7780x over previous
//
#include <hip/hip_runtime.h>
#include <hip/hip_bf16.h>

#define INF_SENT 1.0e6f
#define ALPHA 1.0f
#define INV_BETA 0.5f

#define B_ 16
#define H_ 256
#define W_ 256
#define SEG 8
#define NSEG 32           // H_/SEG
#define NBLK (B_ * NSEG)  // 512 blocks
#define RPAD 16           // vertical halo rows each side

// ---------------------------------------------------------------------------
// Fused self-sufficient kernel: per block (b, 8-row segment)
//   1) vertical two-scan over segment +/- RPAD halo (exact when dist <= RPAD)
//   2) LDS row tiles -> adaptive exact horizontal min (early exit d^2 >= best)
//   3) best >= (RPAD+1)^2  => exact per-pixel global 2D search (window might
//      be truncated; never taken for p=0.5 inputs, keeps exactness always)
//   4) CE + weight -> one partial per block.  No cross-block deps/atomics.
//
// Exactness: window scan gives g_win >= g_true with equality iff g_true<=RPAD.
// Columns with g_true>RPAD contribute >= (RPAD+1)^2 to any pixel's min, so if
// best < (RPAD+1)^2 the window result is the true min; otherwise slow path.
// Early-exit: skipped terms fl(g2[k]+d2) >= d2 >= best (RN monotone).
// ---------------------------------------------------------------------------
__global__ void fused_loss_kernel(const float* __restrict__ pred,
                                  const int* __restrict__ mask,
                                  float* __restrict__ partials) {
    const int bs = blockIdx.x;
    const int b  = bs >> 5;
    const int s  = bs & (NSEG - 1);
    const int j  = threadIdx.x;
    const int i0 = s * SEG;

    __shared__ float s_g2[SEG][W_];
    __shared__ float s_part[4];

    // prefetch logits early; latency hides under the scans
    float pf0[SEG], pf1[SEG];
    const int pb = ((b * 2) << 16) + (i0 << 8) + j;
    #pragma unroll
    for (int r = 0; r < SEG; ++r) {
        pf0[r] = pred[pb + (r << 8)];
        pf1[r] = pred[pb + (r << 8) + H_ * W_];
    }

    const int mb = (b << 16) + j;

    // forward scan: rows i0-RPAD .. i0+SEG-1 (out-of-image -> INF)
    float F[SEG], initOwn[SEG];
    float c = INF_SENT;
    #pragma unroll
    for (int t = 0; t < RPAD + SEG; ++t) {
        const int row = i0 - RPAD + t;            // uniform across block
        float init = INF_SENT;
        if (row >= 0) init = mask[mb + (row << 8)] ? 0.0f : INF_SENT;
        c = fminf(c + 1.0f, init);
        if (t >= RPAD) { F[t - RPAD] = c; initOwn[t - RPAD] = init; }
    }
    // backward scan: rows i0+SEG+RPAD-1 .. i0
    c = INF_SENT;
    #pragma unroll
    for (int t = RPAD + SEG + RPAD - 1; t >= RPAD; --t) {
        const int row = i0 - RPAD + t;
        float init;
        if (t < RPAD + SEG) init = initOwn[t - RPAD];
        else { init = INF_SENT; if (row < H_) init = mask[mb + (row << 8)] ? 0.0f : INF_SENT; }
        c = fminf(c + 1.0f, init);
        if (t < RPAD + SEG) {
            float g = fminf(F[t - RPAD], c);
            s_g2[t - RPAD][j] = g * g;
        }
    }
    __syncthreads();

    // per-row adaptive exact horizontal min + CE + weight
    float vsum = 0.0f;
    #pragma unroll
    for (int r = 0; r < SEG; ++r) {
        float best = s_g2[r][j];
        for (int d = 1; d < W_; ++d) {
            float d2 = (float)(d * d);
            if (d2 >= best) break;
            int kl = j - d, kr = j + d;
            if (kl >= 0)  best = fminf(best, s_g2[r][kl] + d2);
            if (kr < W_)  best = fminf(best, s_g2[r][kr] + d2);
        }

        // window-truncation guard: exact global 2D search (never taken here)
        if (best >= (float)((RPAD + 1) * (RPAD + 1))) {
            const int ii = i0 + r;
            const int mrow = (b << 16);
            int bi = 1 << 28;
            for (int i2 = 0; i2 < H_; ++i2) {
                int dy = i2 - ii, dy2 = dy * dy;
                if (dy2 >= bi) continue;
                for (int j2 = 0; j2 < W_; ++j2) {
                    if (mask[mrow + (i2 << 8) + j2]) {
                        int dx = j2 - j;
                        int dd = dy2 + dx * dx;
                        if (dd < bi) bi = dd;
                    }
                }
            }
            best = (bi < (1 << 28)) ? (float)bi : 1.0e12f;  // empty image -> w=0
        }

        float w = __expf(-sqrtf(best) * INV_BETA);

        // 2-class CE = softplus(-(p_t - p_other))
        float z  = (initOwn[r] == 0.0f) ? (pf1[r] - pf0[r]) : (pf0[r] - pf1[r]);
        float ce = __logf(1.0f + __expf(-z));
        vsum += ce * (1.0f + ALPHA * w);
    }

    // block reduction -> one partial
    for (int off = 32; off > 0; off >>= 1)
        vsum += __shfl_down(vsum, off, 64);
    const int lane = j & 63;
    const int wid  = j >> 6;
    if (lane == 0) s_part[wid] = vsum;
    __syncthreads();
    if (j == 0)
        partials[bs] = s_part[0] + s_part[1] + s_part[2] + s_part[3];
}

// ---------------------------------------------------------------------------
// Final deterministic reduction of NBLK partials -> mean.
// ---------------------------------------------------------------------------
__global__ void final_reduce_kernel(const float* __restrict__ partials,
                                    float* __restrict__ out,
                                    float scale) {
    __shared__ float s_part[8];
    const int t = threadIdx.x;           // 512 threads
    float v = partials[t];
    for (int off = 32; off > 0; off >>= 1)
        v += __shfl_down(v, off, 64);
    if ((t & 63) == 0) s_part[t >> 6] = v;
    __syncthreads();
    if (t == 0) {
        float ssum = 0.0f;
        #pragma unroll
        for (int k = 0; k < 8; ++k) ssum += s_part[k];
        out[0] = ssum * scale;
    }
}

extern "C" void kernel_launch(void* const* d_in, const int* in_sizes, int n_in,
                              void* d_out, int out_size, void* d_ws, size_t ws_size,
                              hipStream_t stream) {
    const float* pred = (const float*)d_in[0];          // [B,2,H,W] f32
    const int*   mask = (const int*)d_in[1];            // [B,H,W] i32
    float* out = (float*)d_out;

    float* partials = (float*)d_ws;                     // NBLK floats

    fused_loss_kernel<<<NBLK, W_, 0, stream>>>(pred, mask, partials);
    final_reduce_kernel<<<1, NBLK, 0, stream>>>(partials, out,
                                                1.0f / (float)(B_ * H_ * W_));
}